// Round 1
// baseline (408.416 us; speedup 1.0000x reference)
//
#include <hip/hip_runtime.h>

#define NUM_BINS 256
#define NPI (3*512*512)   // 786432 elements per image
#define TPB 256
#define MM_BLOCKS 16      // blocks per image for minmax & hist passes
#define NSUB 16           // LDS sub-histograms per block
#define SUBSTRIDE 257     // +1 padding: 257%32==1 -> different banks across subs

// Order-preserving map float -> uint so atomicMin/Max on uint give float min/max.
__device__ __forceinline__ unsigned fmap(float f) {
  unsigned u = __float_as_uint(f);
  return (u & 0x80000000u) ? ~u : (u | 0x80000000u);
}
__device__ __forceinline__ float funmap(unsigned m) {
  unsigned u = (m & 0x80000000u) ? (m ^ 0x80000000u) : ~m;
  return __uint_as_float(u);
}

// Must bit-match the f32 reference: (v-mn)*255 / (mx-mn+1e-8), clip, trunc.
__device__ __forceinline__ int bin_of(float v, float mn, float denom) {
  float norm = (v - mn) * 255.0f / denom;
  norm = fminf(fmaxf(norm, 0.0f), 255.0f);
  return (int)norm;
}

__global__ void init_ws(unsigned* __restrict__ minmax, int* __restrict__ hist) {
  int b = blockIdx.x;
  hist[b * NUM_BINS + threadIdx.x] = 0;
  if (threadIdx.x == 0) { minmax[2*b] = 0xFFFFFFFFu; minmax[2*b+1] = 0u; }
}

__global__ void minmax_k(const float4* __restrict__ x, unsigned* __restrict__ minmax) {
  const int chunk4 = NPI / 4 / MM_BLOCKS;  // 12288 float4 per block
  int img = blockIdx.x / MM_BLOCKS;
  int blk = blockIdx.x % MM_BLOCKS;
  const float4* p = x + (size_t)img * (NPI/4) + (size_t)blk * chunk4;
  float mn = 3.4e38f, mx = -3.4e38f;
  for (int i = threadIdx.x; i < chunk4; i += TPB) {
    float4 v = p[i];
    mn = fminf(mn, fminf(fminf(v.x, v.y), fminf(v.z, v.w)));
    mx = fmaxf(mx, fmaxf(fmaxf(v.x, v.y), fmaxf(v.z, v.w)));
  }
  for (int off = 32; off > 0; off >>= 1) {
    mn = fminf(mn, __shfl_down(mn, off));
    mx = fmaxf(mx, __shfl_down(mx, off));
  }
  __shared__ float smn[4], smx[4];
  int wave = threadIdx.x >> 6, lane = threadIdx.x & 63;
  if (lane == 0) { smn[wave] = mn; smx[wave] = mx; }
  __syncthreads();
  if (threadIdx.x == 0) {
    mn = fminf(fminf(smn[0], smn[1]), fminf(smn[2], smn[3]));
    mx = fmaxf(fmaxf(smx[0], smx[1]), fmaxf(smx[2], smx[3]));
    atomicMin(&minmax[2*img],   fmap(mn));
    atomicMax(&minmax[2*img+1], fmap(mx));
  }
}

__global__ void hist_k(const float4* __restrict__ x,
                       const unsigned* __restrict__ minmax,
                       int* __restrict__ hist) {
  __shared__ int sh[NSUB * SUBSTRIDE];
  for (int i = threadIdx.x; i < NSUB * SUBSTRIDE; i += TPB) sh[i] = 0;
  const int chunk4 = NPI / 4 / MM_BLOCKS;
  int img = blockIdx.x / MM_BLOCKS;
  int blk = blockIdx.x % MM_BLOCKS;
  float mn = funmap(minmax[2*img]);
  float mx = funmap(minmax[2*img+1]);
  float denom = mx - mn + 1e-8f;
  __syncthreads();
  const float4* p = x + (size_t)img * (NPI/4) + (size_t)blk * chunk4;
  int* mysub = sh + (threadIdx.x % NSUB) * SUBSTRIDE;
  for (int i = threadIdx.x; i < chunk4; i += TPB) {
    float4 v = p[i];
    atomicAdd(&mysub[bin_of(v.x, mn, denom)], 1);
    atomicAdd(&mysub[bin_of(v.y, mn, denom)], 1);
    atomicAdd(&mysub[bin_of(v.z, mn, denom)], 1);
    atomicAdd(&mysub[bin_of(v.w, mn, denom)], 1);
  }
  __syncthreads();
  int bin = threadIdx.x;
  int s = 0;
  #pragma unroll
  for (int c = 0; c < NSUB; ++c) s += sh[c * SUBSTRIDE + bin];
  atomicAdd(&hist[img * NUM_BINS + bin], s);
}

__global__ void scan_k(const int* __restrict__ hist, float* __restrict__ cdfn) {
  __shared__ int s[NUM_BINS];
  int img = blockIdx.x, t = threadIdx.x;
  s[t] = hist[img * NUM_BINS + t];
  __syncthreads();
  for (int off = 1; off < NUM_BINS; off <<= 1) {
    int add = (t >= off) ? s[t - off] : 0;
    __syncthreads();
    s[t] += add;
    __syncthreads();
  }
  int cdf = s[t], c0 = s[0], cN = s[NUM_BINS - 1];
  // counts are exact integers < 2^24, so int math == the reference's f32 cumsum
  cdfn[img * NUM_BINS + t] = (float)(cdf - c0) / ((float)(cN - c0) + 1e-8f);
}

__global__ void gather_k(const float4* __restrict__ x,
                         const unsigned* __restrict__ minmax,
                         const float* __restrict__ cdfn,
                         float4* __restrict__ out) {
  const int bpi = NPI / 4 / TPB;  // 768 blocks per image
  int img = blockIdx.x / bpi;
  int blk = blockIdx.x % bpi;
  size_t off = (size_t)img * (NPI/4) + (size_t)blk * TPB + threadIdx.x;
  float mn = funmap(minmax[2*img]);
  float mx = funmap(minmax[2*img+1]);
  float denom = mx - mn + 1e-8f;
  const float* c = cdfn + img * NUM_BINS;
  float4 v = x[off];
  float4 o;
  o.x = c[bin_of(v.x, mn, denom)];
  o.y = c[bin_of(v.y, mn, denom)];
  o.z = c[bin_of(v.z, mn, denom)];
  o.w = c[bin_of(v.w, mn, denom)];
  out[off] = o;
}

extern "C" void kernel_launch(void* const* d_in, const int* in_sizes, int n_in,
                              void* d_out, int out_size, void* d_ws, size_t ws_size,
                              hipStream_t stream) {
  const float* x = (const float*)d_in[0];
  float* out = (float*)d_out;
  int B = in_sizes[0] / NPI;  // 64 images

  // workspace layout: [minmax: 2*B uint][hist: B*256 int][cdfn: B*256 float]
  unsigned* minmax = (unsigned*)d_ws;
  int* hist  = (int*)((char*)d_ws + (size_t)2 * B * sizeof(unsigned));
  float* cdfn = (float*)((char*)d_ws + (size_t)2 * B * sizeof(unsigned)
                                      + (size_t)B * NUM_BINS * sizeof(int));

  init_ws<<<B, NUM_BINS, 0, stream>>>(minmax, hist);
  minmax_k<<<B * MM_BLOCKS, TPB, 0, stream>>>((const float4*)x, minmax);
  hist_k<<<B * MM_BLOCKS, TPB, 0, stream>>>((const float4*)x, minmax, hist);
  scan_k<<<B, NUM_BINS, 0, stream>>>(hist, cdfn);
  gather_k<<<B * (NPI/4/TPB), TPB, 0, stream>>>((const float4*)x, minmax, cdfn, (float4*)out);
}

// Round 2
// 400.561 us; speedup vs baseline: 1.0196x; 1.0196x over previous
//
#include <hip/hip_runtime.h>

#define NUM_BINS 256
#define NPI (3*512*512)   // 786432 elements per image
#define TPB 256
#define MM_BLOCKS 16      // blocks per image for minmax & hist passes
#define NSUB 16           // LDS sub-histograms per block
#define SUBSTRIDE 257     // +1 padding: bank=(sub+bin)%32 -> spread across banks
#define G_VEC 4           // float4 per thread per iter in gather

// Order-preserving map float -> uint so atomicMin/Max on uint give float min/max.
__device__ __forceinline__ unsigned fmap(float f) {
  unsigned u = __float_as_uint(f);
  return (u & 0x80000000u) ? ~u : (u | 0x80000000u);
}
__device__ __forceinline__ float funmap(unsigned m) {
  unsigned u = (m & 0x80000000u) ? (m ^ 0x80000000u) : ~m;
  return __uint_as_float(u);
}

// Must bit-match the f32 reference: (v-mn)*255 / (mx-mn+1e-8), clip, trunc.
// Keep the real division — a reciprocal precompute shifts boundary bins.
__device__ __forceinline__ int bin_of(float v, float mn, float denom) {
  float norm = (v - mn) * 255.0f / denom;
  norm = fminf(fmaxf(norm, 0.0f), 255.0f);
  return (int)norm;
}

__global__ void init_ws(unsigned* __restrict__ minmax, int* __restrict__ hist) {
  int b = blockIdx.x;
  hist[b * NUM_BINS + threadIdx.x] = 0;
  if (threadIdx.x == 0) { minmax[2*b] = 0xFFFFFFFFu; minmax[2*b+1] = 0u; }
}

__global__ void minmax_k(const float4* __restrict__ x, unsigned* __restrict__ minmax) {
  const int chunk4 = NPI / 4 / MM_BLOCKS;  // 12288 float4 per block
  int img = blockIdx.x / MM_BLOCKS;
  int blk = blockIdx.x % MM_BLOCKS;
  const float4* p = x + (size_t)img * (NPI/4) + (size_t)blk * chunk4;
  float mn = 3.4e38f, mx = -3.4e38f;
  for (int i = threadIdx.x; i < chunk4; i += TPB) {
    float4 v = p[i];
    mn = fminf(mn, fminf(fminf(v.x, v.y), fminf(v.z, v.w)));
    mx = fmaxf(mx, fmaxf(fmaxf(v.x, v.y), fmaxf(v.z, v.w)));
  }
  for (int off = 32; off > 0; off >>= 1) {
    mn = fminf(mn, __shfl_down(mn, off));
    mx = fmaxf(mx, __shfl_down(mx, off));
  }
  __shared__ float smn[4], smx[4];
  int wave = threadIdx.x >> 6, lane = threadIdx.x & 63;
  if (lane == 0) { smn[wave] = mn; smx[wave] = mx; }
  __syncthreads();
  if (threadIdx.x == 0) {
    mn = fminf(fminf(smn[0], smn[1]), fminf(smn[2], smn[3]));
    mx = fmaxf(fmaxf(smx[0], smx[1]), fmaxf(smx[2], smx[3]));
    atomicMin(&minmax[2*img],   fmap(mn));
    atomicMax(&minmax[2*img+1], fmap(mx));
  }
}

__global__ void hist_k(const float4* __restrict__ x,
                       const unsigned* __restrict__ minmax,
                       int* __restrict__ hist) {
  __shared__ int sh[NSUB * SUBSTRIDE];
  for (int i = threadIdx.x; i < NSUB * SUBSTRIDE; i += TPB) sh[i] = 0;
  const int chunk4 = NPI / 4 / MM_BLOCKS;  // 12288
  int img = blockIdx.x / MM_BLOCKS;
  int blk = blockIdx.x % MM_BLOCKS;
  float mn = funmap(minmax[2*img]);
  float mx = funmap(minmax[2*img+1]);
  float denom = mx - mn + 1e-8f;
  __syncthreads();
  const float4* p = x + (size_t)img * (NPI/4) + (size_t)blk * chunk4;
  int* mysub = sh + (threadIdx.x % NSUB) * SUBSTRIDE;
  // 4x unroll: 4 in-flight float4 loads, then 16 LDS atomics (latency overlap)
  for (int i = threadIdx.x; i < chunk4; i += TPB * 4) {
    float4 v0 = p[i];
    float4 v1 = p[i + TPB];
    float4 v2 = p[i + 2*TPB];
    float4 v3 = p[i + 3*TPB];
    atomicAdd(&mysub[bin_of(v0.x, mn, denom)], 1);
    atomicAdd(&mysub[bin_of(v0.y, mn, denom)], 1);
    atomicAdd(&mysub[bin_of(v0.z, mn, denom)], 1);
    atomicAdd(&mysub[bin_of(v0.w, mn, denom)], 1);
    atomicAdd(&mysub[bin_of(v1.x, mn, denom)], 1);
    atomicAdd(&mysub[bin_of(v1.y, mn, denom)], 1);
    atomicAdd(&mysub[bin_of(v1.z, mn, denom)], 1);
    atomicAdd(&mysub[bin_of(v1.w, mn, denom)], 1);
    atomicAdd(&mysub[bin_of(v2.x, mn, denom)], 1);
    atomicAdd(&mysub[bin_of(v2.y, mn, denom)], 1);
    atomicAdd(&mysub[bin_of(v2.z, mn, denom)], 1);
    atomicAdd(&mysub[bin_of(v2.w, mn, denom)], 1);
    atomicAdd(&mysub[bin_of(v3.x, mn, denom)], 1);
    atomicAdd(&mysub[bin_of(v3.y, mn, denom)], 1);
    atomicAdd(&mysub[bin_of(v3.z, mn, denom)], 1);
    atomicAdd(&mysub[bin_of(v3.w, mn, denom)], 1);
  }
  __syncthreads();
  int bin = threadIdx.x;
  int s = 0;
  #pragma unroll
  for (int c = 0; c < NSUB; ++c) s += sh[c * SUBSTRIDE + bin];
  atomicAdd(&hist[img * NUM_BINS + bin], s);
}

__global__ void scan_k(const int* __restrict__ hist, float* __restrict__ cdfn) {
  __shared__ int s[NUM_BINS];
  int img = blockIdx.x, t = threadIdx.x;
  s[t] = hist[img * NUM_BINS + t];
  __syncthreads();
  for (int off = 1; off < NUM_BINS; off <<= 1) {
    int add = (t >= off) ? s[t - off] : 0;
    __syncthreads();
    s[t] += add;
    __syncthreads();
  }
  int cdf = s[t], c0 = s[0], cN = s[NUM_BINS - 1];
  // counts are exact integers < 2^24, so int math == the reference's f32 cumsum
  cdfn[img * NUM_BINS + t] = (float)(cdf - c0) / ((float)(cN - c0) + 1e-8f);
}

__global__ void gather_k(const float4* __restrict__ x,
                         const unsigned* __restrict__ minmax,
                         const float* __restrict__ cdfn,
                         float4* __restrict__ out) {
  __shared__ float c[NUM_BINS];  // LDS cdf table: per-lane random read is ~free
  const int f4pi = NPI / 4;              // 196608
  const int CHUNK = TPB * G_VEC;         // 1024 float4 per block
  const int bpi = f4pi / CHUNK;          // 192 blocks per image
  int img = blockIdx.x / bpi;
  int blk = blockIdx.x % bpi;
  c[threadIdx.x] = cdfn[img * NUM_BINS + threadIdx.x];  // TPB==NUM_BINS
  float mn = funmap(minmax[2*img]);
  float denom = funmap(minmax[2*img+1]) - mn + 1e-8f;
  __syncthreads();
  size_t base = (size_t)img * f4pi + (size_t)blk * CHUNK + threadIdx.x;
  #pragma unroll
  for (int j = 0; j < G_VEC; ++j) {
    float4 v = x[base + (size_t)j * TPB];
    float4 o;
    o.x = c[bin_of(v.x, mn, denom)];
    o.y = c[bin_of(v.y, mn, denom)];
    o.z = c[bin_of(v.z, mn, denom)];
    o.w = c[bin_of(v.w, mn, denom)];
    out[base + (size_t)j * TPB] = o;
  }
}

extern "C" void kernel_launch(void* const* d_in, const int* in_sizes, int n_in,
                              void* d_out, int out_size, void* d_ws, size_t ws_size,
                              hipStream_t stream) {
  const float* x = (const float*)d_in[0];
  float* out = (float*)d_out;
  int B = in_sizes[0] / NPI;  // 64 images

  // workspace layout: [minmax: 2*B uint][hist: B*256 int][cdfn: B*256 float]
  unsigned* minmax = (unsigned*)d_ws;
  int* hist  = (int*)((char*)d_ws + (size_t)2 * B * sizeof(unsigned));
  float* cdfn = (float*)((char*)d_ws + (size_t)2 * B * sizeof(unsigned)
                                      + (size_t)B * NUM_BINS * sizeof(int));

  init_ws<<<B, NUM_BINS, 0, stream>>>(minmax, hist);
  minmax_k<<<B * MM_BLOCKS, TPB, 0, stream>>>((const float4*)x, minmax);
  hist_k<<<B * MM_BLOCKS, TPB, 0, stream>>>((const float4*)x, minmax, hist);
  scan_k<<<B, NUM_BINS, 0, stream>>>(hist, cdfn);
  gather_k<<<B * (NPI/4/(TPB*G_VEC)), TPB, 0, stream>>>((const float4*)x, minmax, cdfn, (float4*)out);
}